// Round 4
// baseline (293.755 us; speedup 1.0000x reference)
//
#include <hip/hip_runtime.h>

#define NFFT  2048
#define KF    1025
#define MROWS 2050
#define TT    513
#define HOPS  512
#define LSIG  262144
#define PADL  1024
#define XPADN 264192              // LSIG + 2*PADL
#define XDN   66048               // XPADN / 4 (deinterleaved plane length)
#define IMOFF (16 * MROWS * TT)
#define NBC   32
#define APL   262144              // A elements per r-plane (512*512)
#define BPL   (NBC * XDN)         // xd elements per r-plane

typedef __attribute__((ext_vector_type(8))) short bf16x8;
typedef __attribute__((ext_vector_type(4))) short bf16x4;
typedef __attribute__((ext_vector_type(4))) float f32x4;

__device__ __forceinline__ short f2bf(float f) {
    union { float f; unsigned u; } v; v.f = f;
    unsigned r = v.u + 0x7fffu + ((v.u >> 16) & 1u);
    return (short)(r >> 16);
}

typedef __attribute__((address_space(1))) void gas_void;
typedef __attribute__((address_space(3))) void las_void;

__device__ __forceinline__ void gload_lds16(const short* g, short* l) {
    __builtin_amdgcn_global_load_lds((gas_void*)(void*)const_cast<short*>(g),
                                     (las_void*)(void*)l, 16, 0, 0);
}

// ---- prep: reflect-padded x -> bf16 xpad[32][264192] AND deinterleaved xd[4][32][66048]
__global__ __launch_bounds__(256)
void prep_x(const float* __restrict__ x, short* __restrict__ xpad,
            short* __restrict__ xd) {
    const int bc = blockIdx.y;
    const int j4 = (blockIdx.x * 256 + threadIdx.x) * 4;   // 258*256*4 = 264192 exact
    const float* xb = x + (size_t)bc * LSIG;
    float4 v;
    if (j4 >= PADL && j4 + 4 <= PADL + LSIG) {
        v = *(const float4*)(xb + (j4 - PADL));
    } else {
        float t[4];
#pragma unroll
        for (int e = 0; e < 4; e++) {
            int s = j4 + e - PADL;
            if (s < 0) s = -s;
            if (s >= LSIG) s = 2 * LSIG - 2 - s;
            t[e] = xb[s];
        }
        v = make_float4(t[0], t[1], t[2], t[3]);
    }
    bf16x4 b = { f2bf(v.x), f2bf(v.y), f2bf(v.z), f2bf(v.w) };
    *(bf16x4*)(xpad + (size_t)bc * XPADN + j4) = b;
    const int j = j4 >> 2;                                 // n = 4j + r
#pragma unroll
    for (int r = 0; r < 4; r++)
        xd[((size_t)r * NBC + bc) * XDN + j] = b[r];
}

// ---- prep: twiddle-baked radix-4 basis.
// A'[r][row=2kap+reim][m] = (reim ? wi : wr)[kap][4m+r]  (pure gather, no trig)
__global__ __launch_bounds__(256)
void prep_basis2(const float* __restrict__ wr, const float* __restrict__ wi,
                 short* __restrict__ A) {
    const int r   = blockIdx.y;
    const int row = blockIdx.x;               // 0..511, kap = row>>1
    const float* w = ((row & 1) ? wi : wr) + (size_t)(row >> 1) * NFFT + r;
    short* dst = A + ((size_t)r * 512 + row) * 512;
    for (int m = threadIdx.x; m < 512; m += 256)
        dst[m] = f2bf(w[4 * m]);
}

// ---- fused radix-4 GEMM + combine epilogue, 2-phase double-buffered pipeline.
// Block: 128 basis rows (64 kaps) x 64 t; 8 waves (2M x 4T), wave = 64 rows x 16 t.
// Step = one (r-plane, 64-K) subtile; 32 steps; stage buf[cur^1] BEFORE compute(buf[cur]);
// single end-of-step __syncthreads (vmcnt drain lands after compute => latency hidden).
// acc[r][i]: statically indexed (r unrolled). blockIdx.z == 8 covers only t=512.
__global__ __launch_bounds__(512, 4)
void stft_gemm_f(const short* __restrict__ Ab, const short* __restrict__ xd,
                 float* __restrict__ out) {
    __shared__ short As[2][128 * 64];
    __shared__ short Bs[2][64 * 64];

    const int tid   = threadIdx.x;
    const int bcg   = blockIdx.x;
    const int mBase = blockIdx.y * 128;
    const int t0    = blockIdx.z * 64;

    const int lane = tid & 63;
    const int wid  = tid >> 6;                 // 0..7
    const int wm   = (wid >> 2) * 64;          // 2 M-groups of 64 rows
    const int wn   = (wid & 3) * 16;           // 4 T-groups of 16 t
    const int l16  = lane & 15;
    const int quad = lane >> 4;

    const int lrow = lane >> 3;
    const int csrc = (lane & 7) ^ lrow;

    // staging (per wave, per step): A rows [16w,16w+16), B rows [8w,8w+8)
    const int raw = 16 * wid;
    const int rbw = 8 * wid;
    int brw = t0 + rbw + lrow; if (brw > 512) brw = 512;   // clamp: valid + in-plane

    // per-lane global bases (plane/kt added as offsets)
    const short* aBase = Ab + ((size_t)(mBase + raw + lrow)) * 512 + csrc * 8;
    const short* bBase = xd + (size_t)bcg * XDN + (size_t)brw * 128 + csrc * 8;

    f32x4 acc[4][4];
#pragma unroll
    for (int r = 0; r < 4; r++)
#pragma unroll
        for (int i = 0; i < 4; i++)
            acc[r][i] = (f32x4){0.f, 0.f, 0.f, 0.f};

    const int r7 = l16 & 7;

    // prologue: stage step (r=0, kt=0) into buf0, full drain once
    gload_lds16(aBase,            &As[0][(raw + 0) * 64]);
    gload_lds16(aBase + 8 * 512,  &As[0][(raw + 8) * 64]);
    gload_lds16(bBase,            &Bs[0][rbw * 64]);
    __syncthreads();

#pragma unroll
    for (int r = 0; r < 4; r++) {
        const size_t aR = (size_t)r * APL;
        const size_t bR = (size_t)r * BPL;
        for (int kt = 0; kt < 512; kt += 64) {
            const int cur = (kt >> 6) & 1;
            // issue next-step stage into buf[cur^1] (skip after very last step)
            if (r < 3 || kt < 448) {
                const size_t aN = (kt < 448) ? (aR + kt + 64) : (aR + APL);
                const size_t bN = (kt < 448) ? (bR + kt + 64) : (bR + BPL);
                short* Asn = As[cur ^ 1];
                short* Bsn = Bs[cur ^ 1];
                gload_lds16(aBase + aN,           &Asn[(raw + 0) * 64]);
                gload_lds16(aBase + aN + 8 * 512, &Asn[(raw + 8) * 64]);
                gload_lds16(bBase + bN,           &Bsn[rbw * 64]);
            }
            // compute current buffer
            const short* Asc = As[cur];
            const short* Bsc = Bs[cur];
#pragma unroll
            for (int kk = 0; kk < 64; kk += 32) {
                const int p = ((kk >> 5) * 4 + quad) ^ r7;
                bf16x8 af[4];
#pragma unroll
                for (int i = 0; i < 4; i++)
                    af[i] = *(const bf16x8*)(Asc + (wm + i * 16 + l16) * 64 + p * 8);
                const bf16x8 bfr = *(const bf16x8*)(Bsc + (wn + l16) * 64 + p * 8);
#pragma unroll
                for (int i = 0; i < 4; i++)
                    acc[r][i] = __builtin_amdgcn_mfma_f32_16x16x32_bf16(
                        af[i], bfr, acc[r][i], 0, 0, 0);
            }
            // single barrier per step: drains this step's prefetch AFTER compute
            __syncthreads();
        }
    }

    float* oRe = out + (size_t)bcg * KF * TT;
    float* oIm = out + (size_t)IMOFF + (size_t)bcg * KF * TT;

    const int t = t0 + wn + l16;
    if (t < TT) {
#pragma unroll
        for (int i = 0; i < 4; i++) {
            const int rowb = mBase + wm + i * 16 + quad * 4;
#pragma unroll
            for (int h = 0; h < 2; h++) {
                const int kap = (rowb >> 1) + h;
                const float u0 = acc[0][i][2 * h], v0 = acc[0][i][2 * h + 1];
                const float u1 = acc[1][i][2 * h], v1 = acc[1][i][2 * h + 1];
                const float u2 = acc[2][i][2 * h], v2 = acc[2][i][2 * h + 1];
                const float u3 = acc[3][i][2 * h], v3 = acc[3][i][2 * h + 1];
                const float Eu = u0 + u2, Epu = u0 - u2;
                const float Ou = u1 + u3, Opu = u1 - u3;
                const float Ev = v0 + v2, Epv = v0 - v2;
                const float Ov = v1 + v3, Opv = v1 - v3;
                const size_t rA = (size_t)kap * TT + t;
                const size_t rB = (size_t)(kap + 512) * TT + t;
                const size_t rC = (size_t)(512 - kap) * TT + t;
                const size_t rD = (size_t)(1024 - kap) * TT + t;
                oRe[rA] = Eu + Ou;    oIm[rA] = Ev + Ov;
                oRe[rB] = Epu + Opv;  oIm[rB] = Epv - Opu;
                oRe[rC] = Epu - Opv;  oIm[rC] = -(Epv + Opu);
                oRe[rD] = Eu - Ou;    oIm[rD] = -(Ev - Ov);
            }
        }
    }
}

// ---- tail: k in {256,768} re/im, t in [0,513)  (t=512 via clamped frame row)
__global__ __launch_bounds__(256)
void stft_tail(const float* __restrict__ wr, const float* __restrict__ wi,
               const short* __restrict__ xpad, float* __restrict__ out) {
    const int tb  = blockIdx.x;          // 0..8
    const int bc  = blockIdx.y;          // 0..31
    const int tid = threadIdx.x;
    const int lane = tid & 63;
    const int wid  = tid >> 6;
    const int l16  = lane & 15;
    const int quad = lane >> 4;

    const int t0 = (tb * 4 + wid) * 16;  // 0..560
    const int ls = l16 & 3;
    const int k  = 256 + (ls & 1) * 512;
    const float* bp = ((ls & 2) ? wi : wr) + (size_t)k * NFFT + quad * 8;
    const int tr = min(t0 + l16, 512);
    const short* ap = xpad + (size_t)bc * XPADN + (size_t)tr * HOPS + quad * 8;
    f32x4 acc0 = {0.f, 0.f, 0.f, 0.f}, acc1 = {0.f, 0.f, 0.f, 0.f};
    for (int kt = 0; kt < NFFT; kt += 64) {
        bf16x8 a0 = *(const bf16x8*)(ap + kt);
        bf16x8 a1 = *(const bf16x8*)(ap + kt + 32);
        float4 f0 = *(const float4*)(bp + kt), f1 = *(const float4*)(bp + kt + 4);
        float4 g0 = *(const float4*)(bp + kt + 32), g1 = *(const float4*)(bp + kt + 36);
        bf16x8 b0 = { f2bf(f0.x), f2bf(f0.y), f2bf(f0.z), f2bf(f0.w),
                      f2bf(f1.x), f2bf(f1.y), f2bf(f1.z), f2bf(f1.w) };
        bf16x8 b1 = { f2bf(g0.x), f2bf(g0.y), f2bf(g0.z), f2bf(g0.w),
                      f2bf(g1.x), f2bf(g1.y), f2bf(g1.z), f2bf(g1.w) };
        acc0 = __builtin_amdgcn_mfma_f32_16x16x32_bf16(a0, b0, acc0, 0, 0, 0);
        acc1 = __builtin_amdgcn_mfma_f32_16x16x32_bf16(a1, b1, acc1, 0, 0, 0);
    }
    if (l16 < 4) {
        size_t base = ((ls & 2) ? (size_t)IMOFF : 0) + (size_t)(bc * KF + k) * TT;
#pragma unroll
        for (int rr = 0; rr < 4; rr++) {
            int t = t0 + quad * 4 + rr;
            if (t < TT) out[base + t] = acc0[rr] + acc1[rr];
        }
    }
}

extern "C" void kernel_launch(void* const* d_in, const int* in_sizes, int n_in,
                              void* d_out, int out_size, void* d_ws, size_t ws_size,
                              hipStream_t stream) {
    const float* x  = (const float*)d_in[0];
    const float* wr = (const float*)d_in[1];
    const float* wi = (const float*)d_in[2];
    float* out = (float*)d_out;

    char* ws = (char*)d_ws;
    short* xpad = (short*)ws;                                  // 16,908,288 B
    short* xd   = (short*)(ws + 16908288);                     // 16,908,288 B
    short* Ab   = (short*)(ws + 33816576);                     //  2,097,152 B

    prep_x<<<dim3(258, NBC), 256, 0, stream>>>(x, xpad, xd);
    prep_basis2<<<dim3(512, 4), 256, 0, stream>>>(wr, wi, Ab);
    stft_gemm_f<<<dim3(NBC, 4, 9), 512, 0, stream>>>(Ab, xd, out);
    stft_tail<<<dim3(9, NBC), 256, 0, stream>>>(wr, wi, xpad, out);
}

// Round 5
// 293.444 us; speedup vs baseline: 1.0011x; 1.0011x over previous
//
#include <hip/hip_runtime.h>

#define NFFT  2048
#define KF    1025
#define MROWS 2050
#define TT    513
#define HOPS  512
#define LSIG  262144
#define PADL  1024
#define XPADN 264192              // LSIG + 2*PADL
#define XDN   66048               // XPADN / 4 (deinterleaved plane length)
#define IMOFF (16 * MROWS * TT)
#define NBC   32
#define APL   262144              // A elements per r-plane (512*512)

typedef __attribute__((ext_vector_type(8))) short bf16x8;
typedef __attribute__((ext_vector_type(4))) short bf16x4;
typedef __attribute__((ext_vector_type(4))) float f32x4;

__device__ __forceinline__ short f2bf(float f) {
    union { float f; unsigned u; } v; v.f = f;
    unsigned r = v.u + 0x7fffu + ((v.u >> 16) & 1u);
    return (short)(r >> 16);
}

typedef __attribute__((address_space(1))) void gas_void;
typedef __attribute__((address_space(3))) void las_void;

__device__ __forceinline__ void gload_lds16(const short* g, short* l) {
    __builtin_amdgcn_global_load_lds((gas_void*)(void*)const_cast<short*>(g),
                                     (las_void*)(void*)l, 16, 0, 0);
}

// ---- prep: reflect-padded x -> bf16 xpad[32][264192] AND deinterleaved xd[4][32][66048]
__global__ __launch_bounds__(256)
void prep_x(const float* __restrict__ x, short* __restrict__ xpad,
            short* __restrict__ xd) {
    const int bc = blockIdx.y;
    const int j4 = (blockIdx.x * 256 + threadIdx.x) * 4;   // 258*256*4 = 264192 exact
    const float* xb = x + (size_t)bc * LSIG;
    float4 v;
    if (j4 >= PADL && j4 + 4 <= PADL + LSIG) {
        v = *(const float4*)(xb + (j4 - PADL));
    } else {
        float t[4];
#pragma unroll
        for (int e = 0; e < 4; e++) {
            int s = j4 + e - PADL;
            if (s < 0) s = -s;
            if (s >= LSIG) s = 2 * LSIG - 2 - s;
            t[e] = xb[s];
        }
        v = make_float4(t[0], t[1], t[2], t[3]);
    }
    bf16x4 b = { f2bf(v.x), f2bf(v.y), f2bf(v.z), f2bf(v.w) };
    *(bf16x4*)(xpad + (size_t)bc * XPADN + j4) = b;
    const int j = j4 >> 2;                                 // n = 4j + r
#pragma unroll
    for (int r = 0; r < 4; r++)
        xd[((size_t)r * NBC + bc) * XDN + j] = b[r];
}

// ---- prep: twiddle-baked radix-4 basis.
// A'[r][row=2kap+reim][m] = (reim ? wi : wr)[kap][4m+r]  (pure gather, no trig)
__global__ __launch_bounds__(256)
void prep_basis2(const float* __restrict__ wr, const float* __restrict__ wi,
                 short* __restrict__ A) {
    const int r   = blockIdx.y;
    const int row = blockIdx.x;               // 0..511, kap = row>>1
    const float* w = ((row & 1) ? wi : wr) + (size_t)(row >> 1) * NFFT + r;
    short* dst = A + ((size_t)r * 512 + row) * 512;
    for (int m = threadIdx.x; m < 512; m += 256)
        dst[m] = f2bf(w[4 * m]);
}

// ---- fused radix-4 GEMM, plane-per-wave, barrier-free main loop.
// Block: 64 basis rows (32 kaps) x 64 t; 4 waves, wave r owns plane r with a
// 64x64 tile (acc 4x4 frags = 64 VGPR). Each wave stages its PRIVATE 32 KB LDS
// strip (A 8K + B 8K, dbuf, K-step 64) and waits only on its own counted
// vmcnt(16) -> no __syncthreads in the K loop. Butterfly via LDS exchange after.
// blockIdx.z == 8 covers only t=512 (B rows clamped in-plane, stores guarded).
__global__ __launch_bounds__(256, 1)
void stft_gemm_f(const short* __restrict__ Ab, const short* __restrict__ xd,
                 float* __restrict__ out) {
    extern __shared__ short lds[];             // 131072 B

    const int tid  = threadIdx.x;
    const int lane = tid & 63;
    const int r    = tid >> 6;                 // wave id == r-plane
    const int bcg  = blockIdx.x;
    const int mBase = blockIdx.y * 64;
    const int t0    = blockIdx.z * 64;

    const int l16  = lane & 15;
    const int quad = lane >> 4;
    const int lrow = lane >> 3;                // 0..7
    const int csrc = (lane & 7) ^ lrow;
    const int r7   = l16 & 7;

    short* strip = lds + r * 16384;            // 32 KB per wave (shorts)

    // global sources (pre-swizzled chunk per lane; same verified scheme)
    const short* aSrc = Ab + (size_t)r * APL + (size_t)(mBase + lrow) * 512 + csrc * 8;
    const short* bPlane = xd + ((size_t)r * NBC + bcg) * XDN + csrc * 8;
    const short* bSrc[8];
#pragma unroll
    for (int i = 0; i < 8; i++) {
        int bt = t0 + 8 * i + lrow; if (bt > 512) bt = 512;   // in-plane clamp
        bSrc[i] = bPlane + (size_t)bt * 128;
    }

    f32x4 acc[4][4];
#pragma unroll
    for (int i = 0; i < 4; i++)
#pragma unroll
        for (int j = 0; j < 4; j++)
            acc[i][j] = (f32x4){0.f, 0.f, 0.f, 0.f};

    // prologue: stage step 0 into buffer 0 (16 loads)
#pragma unroll
    for (int i = 0; i < 8; i++) {
        gload_lds16(aSrc + i * 4096, strip + i * 512);
        gload_lds16(bSrc[i],         strip + 8192 + i * 512);
    }

    for (int kt = 0; kt < 512; kt += 64) {
        const int cur = (kt >> 6) & 1;
        if (kt < 448) {
            short* dA = strip + ((cur ^ 1) << 12);
            short* dB = strip + 8192 + ((cur ^ 1) << 12);
            const int ko = kt + 64;
#pragma unroll
            for (int i = 0; i < 8; i++) {
                gload_lds16(aSrc + i * 4096 + ko, dA + i * 512);
                gload_lds16(bSrc[i] + ko,         dB + i * 512);
            }
            asm volatile("s_waitcnt vmcnt(16)" ::: "memory");
        } else {
            asm volatile("s_waitcnt vmcnt(0)" ::: "memory");
        }
        __builtin_amdgcn_sched_barrier(0);
        const short* Ac = strip + (cur << 12);
        const short* Bc = strip + 8192 + (cur << 12);
#pragma unroll
        for (int kk = 0; kk < 2; kk++) {
            const int p = (kk * 4 + quad) ^ r7;
            bf16x8 af[4], bfr[4];
#pragma unroll
            for (int i = 0; i < 4; i++)
                af[i] = *(const bf16x8*)(Ac + (i * 16 + l16) * 64 + p * 8);
#pragma unroll
            for (int j = 0; j < 4; j++)
                bfr[j] = *(const bf16x8*)(Bc + (j * 16 + l16) * 64 + p * 8);
#pragma unroll
            for (int i = 0; i < 4; i++)
#pragma unroll
                for (int j = 0; j < 4; j++)
                    acc[i][j] = __builtin_amdgcn_mfma_f32_16x16x32_bf16(
                        af[i], bfr[j], acc[i][j], 0, 0, 0);
        }
    }

    // ---- butterfly via LDS exchange ----
    __syncthreads();
    float* sf = (float*)lds;
    float* Sr = sf + r * (64 * 66);            // stride 66: 2-way banks (free)
#pragma unroll
    for (int i = 0; i < 4; i++)
#pragma unroll
        for (int j = 0; j < 4; j++)
#pragma unroll
            for (int rr = 0; rr < 4; rr++)
                Sr[(i * 16 + quad * 4 + rr) * 66 + j * 16 + l16] = acc[i][j][rr];
    __syncthreads();

    float* oRe = out + (size_t)bcg * KF * TT;
    float* oIm = out + (size_t)IMOFF + (size_t)bcg * KF * TT;
    const int tg = t0 + lane;
    if (tg < TT) {
#pragma unroll
        for (int kl = 0; kl < 8; kl++) {
            const int kap = r * 8 + kl;                 // local kap 0..31
            const int kg  = (mBase >> 1) + kap;         // global kap 0..255
            float u0 = sf[0 * 4224 + (2 * kap) * 66 + lane];
            float v0 = sf[0 * 4224 + (2 * kap + 1) * 66 + lane];
            float u1 = sf[1 * 4224 + (2 * kap) * 66 + lane];
            float v1 = sf[1 * 4224 + (2 * kap + 1) * 66 + lane];
            float u2 = sf[2 * 4224 + (2 * kap) * 66 + lane];
            float v2 = sf[2 * 4224 + (2 * kap + 1) * 66 + lane];
            float u3 = sf[3 * 4224 + (2 * kap) * 66 + lane];
            float v3 = sf[3 * 4224 + (2 * kap + 1) * 66 + lane];
            const float Eu = u0 + u2, Epu = u0 - u2;
            const float Ou = u1 + u3, Opu = u1 - u3;
            const float Ev = v0 + v2, Epv = v0 - v2;
            const float Ov = v1 + v3, Opv = v1 - v3;
            const size_t rA = (size_t)kg * TT + tg;
            const size_t rB = (size_t)(kg + 512) * TT + tg;
            const size_t rC = (size_t)(512 - kg) * TT + tg;
            const size_t rD = (size_t)(1024 - kg) * TT + tg;
            oRe[rA] = Eu + Ou;    oIm[rA] = Ev + Ov;
            oRe[rB] = Epu + Opv;  oIm[rB] = Epv - Opu;
            oRe[rC] = Epu - Opv;  oIm[rC] = -(Epv + Opu);
            oRe[rD] = Eu - Ou;    oIm[rD] = -(Ev - Ov);
        }
    }
}

// ---- tail: k in {256,768} re/im, t in [0,513)  (t=512 via clamped frame row)
__global__ __launch_bounds__(256)
void stft_tail(const float* __restrict__ wr, const float* __restrict__ wi,
               const short* __restrict__ xpad, float* __restrict__ out) {
    const int tb  = blockIdx.x;          // 0..8
    const int bc  = blockIdx.y;          // 0..31
    const int tid = threadIdx.x;
    const int lane = tid & 63;
    const int wid  = tid >> 6;
    const int l16  = lane & 15;
    const int quad = lane >> 4;

    const int t0 = (tb * 4 + wid) * 16;  // 0..560
    const int ls = l16 & 3;
    const int k  = 256 + (ls & 1) * 512;
    const float* bp = ((ls & 2) ? wi : wr) + (size_t)k * NFFT + quad * 8;
    const int tr = min(t0 + l16, 512);
    const short* ap = xpad + (size_t)bc * XPADN + (size_t)tr * HOPS + quad * 8;
    f32x4 acc0 = {0.f, 0.f, 0.f, 0.f}, acc1 = {0.f, 0.f, 0.f, 0.f};
    for (int kt = 0; kt < NFFT; kt += 64) {
        bf16x8 a0 = *(const bf16x8*)(ap + kt);
        bf16x8 a1 = *(const bf16x8*)(ap + kt + 32);
        float4 f0 = *(const float4*)(bp + kt), f1 = *(const float4*)(bp + kt + 4);
        float4 g0 = *(const float4*)(bp + kt + 32), g1 = *(const float4*)(bp + kt + 36);
        bf16x8 b0 = { f2bf(f0.x), f2bf(f0.y), f2bf(f0.z), f2bf(f0.w),
                      f2bf(f1.x), f2bf(f1.y), f2bf(f1.z), f2bf(f1.w) };
        bf16x8 b1 = { f2bf(g0.x), f2bf(g0.y), f2bf(g0.z), f2bf(g0.w),
                      f2bf(g1.x), f2bf(g1.y), f2bf(g1.z), f2bf(g1.w) };
        acc0 = __builtin_amdgcn_mfma_f32_16x16x32_bf16(a0, b0, acc0, 0, 0, 0);
        acc1 = __builtin_amdgcn_mfma_f32_16x16x32_bf16(a1, b1, acc1, 0, 0, 0);
    }
    if (l16 < 4) {
        size_t base = ((ls & 2) ? (size_t)IMOFF : 0) + (size_t)(bc * KF + k) * TT;
#pragma unroll
        for (int rr = 0; rr < 4; rr++) {
            int t = t0 + quad * 4 + rr;
            if (t < TT) out[base + t] = acc0[rr] + acc1[rr];
        }
    }
}

extern "C" void kernel_launch(void* const* d_in, const int* in_sizes, int n_in,
                              void* d_out, int out_size, void* d_ws, size_t ws_size,
                              hipStream_t stream) {
    const float* x  = (const float*)d_in[0];
    const float* wr = (const float*)d_in[1];
    const float* wi = (const float*)d_in[2];
    float* out = (float*)d_out;

    char* ws = (char*)d_ws;
    short* xpad = (short*)ws;                                  // 16,908,288 B
    short* xd   = (short*)(ws + 16908288);                     // 16,908,288 B
    short* Ab   = (short*)(ws + 33816576);                     //  2,097,152 B

    static bool cfgDone = false;
    if (!cfgDone) {
        (void)hipFuncSetAttribute((const void*)stft_gemm_f,
                                  hipFuncAttributeMaxDynamicSharedMemorySize,
                                  131072);
        cfgDone = true;
    }

    prep_x<<<dim3(258, NBC), 256, 0, stream>>>(x, xpad, xd);
    prep_basis2<<<dim3(512, 4), 256, 0, stream>>>(wr, wi, Ab);
    stft_gemm_f<<<dim3(NBC, 8, 9), 256, 131072, stream>>>(Ab, xd, out);
    stft_tail<<<dim3(9, NBC), 256, 0, stream>>>(wr, wi, xpad, out);
}